// Round 3
// baseline (4995.909 us; speedup 1.0000x reference)
//
#include <hip/hip_runtime.h>
#include <cstdio>
#include <cstdint>

// HeteroGraph 3-layer SAGE on MI355X — R3.
// R2 post-mortem: kfill scatter = 250MB WRITE (16x amp), ~900us of CSR build.
// R3: bucket-partition (512 dst-buckets, LDS-rank + per-block segment reserve,
// packed u32 edges) + bucket-block LDS-f32-atomic aggregation (no CSR, no
// per-node cursors, no 200k scans). GEMM -> MFMA bf16 (A-frags from global,
// B=weights transposed in LDS, mean folded into aggSS store).

#define NSUB 200000
#define HDIM 64
#define ESS 2000000
#define EAS 4000000
#define EUS 2000000
#define NB 512
#define CAP_AS 8608   // avg 7812.5 +9 sigma
#define CAP_SS 4320   // avg 3906.25 +6.6 sigma
#define CAP_US 4320
#define CHUNK 4096
#define NCH_AS 977    // ceil(4M/4096)
#define NCH_SS 489
#define NCH_US 489
#define CDIV(a,b) (((a)+(b)-1)/(b))

using u16 = unsigned short;
typedef __attribute__((ext_vector_type(8))) short v8s;
typedef __attribute__((ext_vector_type(4))) float v4f;

__device__ __forceinline__ float bu2f(u16 u){
  union { unsigned int i; float f; } c; c.i = ((unsigned int)u) << 16; return c.f;
}
__device__ __forceinline__ u16 f2bu(float x){
  union { float f; unsigned int i; } c; c.f = x;
  unsigned int r = c.i + 0x7fffu + ((c.i >> 16) & 1u);
  return (u16)(r >> 16);
}
__device__ __forceinline__ int bucket_of(int d){
  return (int)(((unsigned long long)(unsigned)d * NB) / NSUB);
}
__device__ __forceinline__ int bucket_base(int b){
  return (int)(((unsigned long long)b * NSUB + NB - 1) / NB);
}

__global__ void kzero(int* __restrict__ p, int n){
  int i = blockIdx.x*256 + threadIdx.x; if(i<n) p[i]=0;
}

__global__ void kcast(const float4* __restrict__ in, uint2* __restrict__ outp, int n4){
  int i = blockIdx.x*256 + threadIdx.x;
  if(i<n4){
    float4 v = in[i];
    uint2 o;
    o.x = (unsigned int)f2bu(v.x) | ((unsigned int)f2bu(v.y)<<16);
    o.y = (unsigned int)f2bu(v.z) | ((unsigned int)f2bu(v.w)<<16);
    outp[i]=o;
  }
}

// Per-layer weights -> bf16, transposed to [o][k=256] (k: ss,as,us,WrSum), + bias sum.
__global__ void kprep(const float* __restrict__ Wl, const float* __restrict__ Wr,
                      const float* __restrict__ bl, u16* __restrict__ Wg,
                      float* __restrict__ bsum){
  int l = blockIdx.x, tid = threadIdx.x;
  for(int i=tid; i<16384; i+=256){
    int o = i>>8, k = i&255, a = k>>6, kk = k&63;
    float v;
    if(a<3) v = Wl[(((size_t)l*3+a)*64+o)*64+kk];
    else    v = Wr[(((size_t)l*3+0)*64+o)*64+kk]
              + Wr[(((size_t)l*3+1)*64+o)*64+kk]
              + Wr[(((size_t)l*3+2)*64+o)*64+kk];
    Wg[((size_t)l*64+o)*256 + k] = f2bu(v);
  }
  if(tid<64) bsum[l*64+tid] = bl[(l*3+0)*64+tid] + bl[(l*3+1)*64+tid] + bl[(l*3+2)*64+tid];
}

// Fused 3-relation bucket partition. Chunk per block: LDS rank, per-block
// per-bucket global segment reserve, sequential segment writes (L2-merged).
__global__ __launch_bounds__(256) void kpart(
    const int* __restrict__ e_ss, const int* __restrict__ e_as_s,
    const int* __restrict__ e_as_d, const int* __restrict__ e_us,
    unsigned* __restrict__ pAS, unsigned* __restrict__ pSS,
    unsigned* __restrict__ pUS, int* __restrict__ gcur){
  __shared__ int cnt[NB];
  __shared__ int seg[NB];
  int bid = blockIdx.x, tid = threadIdx.x;
  int rel, chunk, cap, Erel;
  const int *sp, *dp; unsigned* part;
  if(bid < NCH_AS){ rel=0; chunk=bid; sp=e_as_s; dp=e_as_d; part=pAS; cap=CAP_AS; Erel=EAS; }
  else if(bid < NCH_AS+NCH_SS){ rel=1; chunk=bid-NCH_AS; sp=e_ss; dp=e_ss+ESS; part=pSS; cap=CAP_SS; Erel=ESS; }
  else { rel=2; chunk=bid-NCH_AS-NCH_SS; sp=e_us; dp=e_us+EUS; part=pUS; cap=CAP_US; Erel=EUS; }
  int m = Erel - chunk*CHUNK; if(m>CHUNK) m=CHUNK;
  for(int i=tid;i<NB;i+=256) cnt[i]=0;
  __syncthreads();
  unsigned pk[16], meta[16];
  #pragma unroll
  for(int j=0;j<16;j++){
    int idx = j*256+tid;
    meta[j] = 0xFFFFFFFFu;
    if(idx < m){
      long i = (long)chunk*CHUNK + idx;
      int s = sp[i], d = dp[i];
      int b = bucket_of(d);
      int r = atomicAdd(&cnt[b],1);
      pk[j] = ((unsigned)s<<9) | (unsigned)(d - bucket_base(b));
      meta[j] = ((unsigned)b<<16) | (unsigned)r;
    }
  }
  __syncthreads();
  for(int q=tid;q<NB;q+=256){
    int c = cnt[q];
    seg[q] = c ? atomicAdd(&gcur[rel*NB+q], c) : 0;
  }
  __syncthreads();
  #pragma unroll
  for(int j=0;j<16;j++){
    if(meta[j]!=0xFFFFFFFFu){
      int b = meta[j]>>16, r = meta[j]&0xFFFF;
      int pos = seg[b] + r;
      if(pos < cap) part[(long)b*cap + pos] = pk[j];
    }
  }
}

__device__ __forceinline__ float gather1(const float* x, size_t idx){ return x[idx]; }
__device__ __forceinline__ float gather1(const u16* x, size_t idx){ return bu2f(x[idx]); }

// Bucket-block aggregation: LDS f32 accumulators (391 nodes x 64 feats),
// degree counts in LDS; MEAN folds 1/deg into the bf16 store.
template<typename T, bool MEAN>
__global__ __launch_bounds__(256) void kaggB(const T* __restrict__ x,
    const unsigned* __restrict__ part, const int* __restrict__ gcur, int cap,
    u16* __restrict__ out){
  __shared__ float acc[391*64];
  __shared__ int cnt[392];
  int b = blockIdx.x, tid = threadIdx.x;
  int base_b = bucket_base(b);
  int base_n = (b+1==NB) ? NSUB : bucket_base(b+1);
  int width = base_n - base_b;
  for(int i=tid;i<width*64;i+=256) acc[i]=0.f;
  for(int i=tid;i<width;i+=256) cnt[i]=0;
  __syncthreads();
  int size = gcur[b]; if(size>cap) size=cap;
  int lane = tid&63, wid = tid>>6;
  const unsigned* pb = part + (long)b*cap;
  int nbat = size>>4;
  for(int bt = wid; bt < nbat; bt += 4){
    int t0 = bt<<4;
    unsigned myw = (lane<16) ? pb[t0+lane] : 0u;
    int srcj[16], dlj[16]; float vj[16];
    #pragma unroll
    for(int j=0;j<16;j++){ unsigned p=__shfl(myw,j); srcj[j]=(int)(p>>9); dlj[j]=(int)(p&511u); }
    #pragma unroll
    for(int j=0;j<16;j++) vj[j] = gather1(x, (size_t)srcj[j]*HDIM + lane);
    #pragma unroll
    for(int j=0;j<16;j++) atomicAdd(&acc[dlj[j]*64 + lane], vj[j]);
    if(lane==0){
      #pragma unroll
      for(int j=0;j<16;j++) atomicAdd(&cnt[dlj[j]], 1);
    }
  }
  int rem = size & 15;
  if(rem && ((nbat & 3) == wid)){
    for(int e = nbat<<4; e < size; e++){
      unsigned p = pb[e];
      int s_ = (int)(p>>9), d_ = (int)(p&511u);
      float v = gather1(x, (size_t)s_*HDIM + lane);
      atomicAdd(&acc[d_*64 + lane], v);
      if(lane==0) atomicAdd(&cnt[d_], 1);
    }
  }
  __syncthreads();
  for(int n = wid; n < width; n += 4){
    float s = 1.f;
    if(MEAN){ int c = cnt[n]; s = 1.f/(float)(c>1?c:1); }
    out[(size_t)(base_b+n)*HDIM + lane] = f2bu(acc[n*64+lane]*s);
  }
}

// MFMA GEMM: out = relu(concat(aggSS,aggAS,aggUS,subIn) @ Wg^T + bsum), bf16.
// A-frag: A[m=lane&15][k=quad*8+j] direct from global; B-frag from LDS
// (Wg transposed [o][k], row stride 264 u16 -> 2-way-free banks).
__global__ __launch_bounds__(256) void kgemmM(
    const u16* __restrict__ aggSS, const u16* __restrict__ aggAS,
    const u16* __restrict__ aggUS, const u16* __restrict__ subIn,
    const u16* __restrict__ Wg, const float* __restrict__ bsum,
    u16* __restrict__ subOut){
  __shared__ u16 ldsW[64*264];
  __shared__ float ldsB[64];
  int tid = threadIdx.x;
  const unsigned* wg32 = (const unsigned*)Wg;   // 8192 dwords = [o=64][k2=128]
  for(int i=tid; i<8192; i+=256){
    int o = i>>7, k2 = i&127;
    ((unsigned*)ldsW)[o*132 + k2] = wg32[i];
  }
  if(tid<64) ldsB[tid] = bsum[tid];
  __syncthreads();
  int lane = tid&63, wid = tid>>6;
  long row0 = (long)blockIdx.x*64 + wid*16;
  const u16* arrs[4] = {aggSS, aggAS, aggUS, subIn};
  v4f acc[4] = {};
  long rowl = row0 + (lane&15);
  int kq = (lane>>4)*8;
  #pragma unroll
  for(int s=0;s<8;s++){
    const u16* ap = arrs[s>>1] + rowl*64 + (s&1)*32 + kq;
    v8s a = *(const v8s*)ap;
    #pragma unroll
    for(int t=0;t<4;t++){
      v8s bf = *(const v8s*)&ldsW[(t*16+(lane&15))*264 + s*32 + kq];
      acc[t] = __builtin_amdgcn_mfma_f32_16x16x32_bf16(a, bf, acc[t], 0,0,0);
    }
  }
  int m0 = (lane>>4)*4;
  #pragma unroll
  for(int t=0;t<4;t++){
    int o = t*16 + (lane&15);
    float bb = ldsB[o];
    #pragma unroll
    for(int r=0;r<4;r++){
      float h = acc[t][r] + bb;
      h = fmaxf(h, 0.f);
      subOut[(row0 + m0 + r)*64 + o] = f2bu(h);
    }
  }
}

// head: softmax(sub @ Wf^T + bf) -> FLOAT32 out
__global__ void khead(const u16* __restrict__ sub, const float* __restrict__ Wf,
                      const float* __restrict__ bfv, float* __restrict__ out, int n){
  __shared__ float w[6*64];
  __shared__ float b[6];
  for(int j=threadIdx.x; j<384; j+=256) w[j]=Wf[j];
  if(threadIdx.x<6) b[threadIdx.x]=bfv[threadIdx.x];
  __syncthreads();
  int i = blockIdx.x*256 + threadIdx.x;
  if(i>=n) return;
  const unsigned int* row = (const unsigned int*)(sub + (size_t)i*HDIM);
  float d0=b[0],d1=b[1],d2=b[2],d3=b[3],d4=b[4],d5=b[5];
  #pragma unroll 8
  for(int k2=0;k2<32;k2++){
    unsigned int v = row[k2];
    float lo = bu2f((u16)(v&0xffffu));
    float hi = bu2f((u16)(v>>16));
    int k = 2*k2;
    d0 += lo*w[0*64+k] + hi*w[0*64+k+1];
    d1 += lo*w[1*64+k] + hi*w[1*64+k+1];
    d2 += lo*w[2*64+k] + hi*w[2*64+k+1];
    d3 += lo*w[3*64+k] + hi*w[3*64+k+1];
    d4 += lo*w[4*64+k] + hi*w[4*64+k+1];
    d5 += lo*w[5*64+k] + hi*w[5*64+k+1];
  }
  float m = fmaxf(fmaxf(fmaxf(d0,d1),fmaxf(d2,d3)),fmaxf(d4,d5));
  float e0=expf(d0-m), e1=expf(d1-m), e2=expf(d2-m);
  float e3=expf(d3-m), e4=expf(d4-m), e5=expf(d5-m);
  float inv = 1.0f/(e0+e1+e2+e3+e4+e5);
  float2* op = (float2*)(out + (size_t)i*6);
  float2 r0; r0.x=e0*inv; r0.y=e1*inv;
  float2 r1; r1.x=e2*inv; r1.y=e3*inv;
  float2 r2; r2.x=e4*inv; r2.y=e5*inv;
  op[0]=r0; op[1]=r1; op[2]=r2;
}

extern "C" void kernel_launch(void* const* d_in, const int* in_sizes, int n_in,
                              void* d_out, int out_size, void* d_ws, size_t ws_size,
                              hipStream_t stream) {
  const float* x_sub = (const float*)d_in[0];
  const float* x_agr = (const float*)d_in[1];
  const float* x_urb = (const float*)d_in[2];
  const float* Wl    = (const float*)d_in[3];  // [3][3][64][64]
  const float* bl    = (const float*)d_in[4];  // [3][3][64]
  const float* Wr    = (const float*)d_in[5];  // [3][3][64][64]
  const float* Wf    = (const float*)d_in[6];  // [6][64]
  const float* bfv   = (const float*)d_in[7];  // [6]
  const int* e_ss    = (const int*)d_in[8];    // [2][ESS]
  const int* e_as_s  = (const int*)d_in[9];
  const int* e_as_d  = (const int*)d_in[10];
  const int* e_us    = (const int*)d_in[11];   // [2][EUS]
  float* out = (float*)d_out;

  char* ws = (char*)d_ws;
  size_t off = 0;
  auto alloc = [&](size_t bytes)->void*{
    void* p = ws + off; off += (bytes + 255) & ~(size_t)255; return p;
  };
  u16*  subA   = (u16*) alloc((size_t)NSUB*HDIM*2);
  u16*  subB   = (u16*) alloc((size_t)NSUB*HDIM*2);
  u16*  aggSS  = (u16*) alloc((size_t)NSUB*HDIM*2);
  u16*  aggAS  = (u16*) alloc((size_t)NSUB*HDIM*2);
  u16*  aggUS  = (u16*) alloc((size_t)NSUB*HDIM*2);
  unsigned* pAS = (unsigned*)alloc((size_t)NB*CAP_AS*4);
  unsigned* pSS = (unsigned*)alloc((size_t)NB*CAP_SS*4);
  unsigned* pUS = (unsigned*)alloc((size_t)NB*CAP_US*4);
  int*  gcur   = (int*)  alloc((size_t)3*NB*4);
  u16*  Wg     = (u16*)  alloc((size_t)3*64*256*2);
  float* bsum  = (float*)alloc((size_t)3*64*4);
  if(off > ws_size){
    fprintf(stderr, "kernel_launch: ws too small: need %zu have %zu\n", off, ws_size);
    return;
  }

  // prep: x_sub -> bf16; weights -> bf16 transposed; gcur = 0
  kcast<<<CDIV(NSUB*HDIM/4,256),256,0,stream>>>((const float4*)x_sub, (uint2*)subA, NSUB*HDIM/4);
  kprep<<<3,256,0,stream>>>(Wl, Wr, bl, Wg, bsum);
  kzero<<<CDIV(3*NB,256),256,0,stream>>>(gcur, 3*NB);

  // bucket partition (all 3 relations)
  kpart<<<NCH_AS+NCH_SS+NCH_US,256,0,stream>>>(e_ss, e_as_s, e_as_d, e_us,
                                               pAS, pSS, pUS, gcur);

  // one-time agr/urb aggregations (features constant across layers)
  kaggB<float,false><<<NB,256,0,stream>>>(x_agr, pAS, gcur + 0*NB, CAP_AS, aggAS);
  kaggB<float,false><<<NB,256,0,stream>>>(x_urb, pUS, gcur + 2*NB, CAP_US, aggUS);

  const int gemmBlocks = NSUB/64;  // 3125 exact
  // layer 0 (ss aggr = sum)
  kaggB<u16,false><<<NB,256,0,stream>>>(subA, pSS, gcur + 1*NB, CAP_SS, aggSS);
  kgemmM<<<gemmBlocks,256,0,stream>>>(aggSS, aggAS, aggUS, subA, Wg + 0*16384, bsum + 0*64, subB);
  // layer 1 (ss aggr = mean)
  kaggB<u16,true><<<NB,256,0,stream>>>(subB, pSS, gcur + 1*NB, CAP_SS, aggSS);
  kgemmM<<<gemmBlocks,256,0,stream>>>(aggSS, aggAS, aggUS, subB, Wg + 1*16384, bsum + 1*64, subA);
  // layer 2 (ss aggr = mean)
  kaggB<u16,true><<<NB,256,0,stream>>>(subA, pSS, gcur + 1*NB, CAP_SS, aggSS);
  kgemmM<<<gemmBlocks,256,0,stream>>>(aggSS, aggAS, aggUS, subA, Wg + 2*16384, bsum + 2*64, subB);

  // head: softmax(sub @ Wf^T + bf) -> f32 out
  khead<<<CDIV(NSUB,256),256,0,stream>>>(subB, Wf, bfv, out, NSUB);
}

// Round 4
// 1032.189 us; speedup vs baseline: 4.8401x; 4.8401x over previous
//
#include <hip/hip_runtime.h>
#include <cstdio>
#include <cstdint>

// HeteroGraph 3-layer SAGE on MI355X — R4.
// R3 post-mortem: kaggB's 100KB LDS accumulator -> 1 block/CU -> 12% occupancy,
// latency-bound (1505us). R4: keep kpart (cheap bucketing), add per-bucket
// counting sort -> true CSR (writes land in 31KB L2-resident windows), and
// aggregate with R2's wave-per-dst register-accumulate kernel (no LDS, full
// occupancy). MFMA GEMM + head unchanged (verified, absmax 0.0039).

#define NSUB 200000
#define HDIM 64
#define ESS 2000000
#define EAS 4000000
#define EUS 2000000
#define NB 512
#define CAP_AS 8608
#define CAP_SS 4320
#define CAP_US 4320
#define CHUNK 4096
#define NCH_AS 977
#define NCH_SS 489
#define NCH_US 489
#define CDIV(a,b) (((a)+(b)-1)/(b))

using u16 = unsigned short;
typedef __attribute__((ext_vector_type(8))) short v8s;
typedef __attribute__((ext_vector_type(4))) float v4f;

__device__ __forceinline__ float bu2f(u16 u){
  union { unsigned int i; float f; } c; c.i = ((unsigned int)u) << 16; return c.f;
}
__device__ __forceinline__ u16 f2bu(float x){
  union { float f; unsigned int i; } c; c.f = x;
  unsigned int r = c.i + 0x7fffu + ((c.i >> 16) & 1u);
  return (u16)(r >> 16);
}
__device__ __forceinline__ int bucket_of(int d){
  return (int)(((unsigned long long)(unsigned)d * NB) / NSUB);
}
__device__ __forceinline__ int bucket_base(int b){
  return (int)(((unsigned long long)b * NSUB + NB - 1) / NB);
}

__global__ void kzero(int* __restrict__ p, int n){
  int i = blockIdx.x*256 + threadIdx.x; if(i<n) p[i]=0;
}

__global__ void kcast(const float4* __restrict__ in, uint2* __restrict__ outp, int n4){
  int i = blockIdx.x*256 + threadIdx.x;
  if(i<n4){
    float4 v = in[i];
    uint2 o;
    o.x = (unsigned int)f2bu(v.x) | ((unsigned int)f2bu(v.y)<<16);
    o.y = (unsigned int)f2bu(v.z) | ((unsigned int)f2bu(v.w)<<16);
    outp[i]=o;
  }
}

// Per-layer weights -> bf16, transposed to [o][k=256] (k: ss,as,us,WrSum), + bias sum.
__global__ void kprep(const float* __restrict__ Wl, const float* __restrict__ Wr,
                      const float* __restrict__ bl, u16* __restrict__ Wg,
                      float* __restrict__ bsum){
  int l = blockIdx.x, tid = threadIdx.x;
  for(int i=tid; i<16384; i+=256){
    int o = i>>8, k = i&255, a = k>>6, kk = k&63;
    float v;
    if(a<3) v = Wl[(((size_t)l*3+a)*64+o)*64+kk];
    else    v = Wr[(((size_t)l*3+0)*64+o)*64+kk]
              + Wr[(((size_t)l*3+1)*64+o)*64+kk]
              + Wr[(((size_t)l*3+2)*64+o)*64+kk];
    Wg[((size_t)l*64+o)*256 + k] = f2bu(v);
  }
  if(tid<64) bsum[l*64+tid] = bl[(l*3+0)*64+tid] + bl[(l*3+1)*64+tid] + bl[(l*3+2)*64+tid];
}

// Fused 3-relation bucket partition (unchanged from R3 — validated).
__global__ __launch_bounds__(256) void kpart(
    const int* __restrict__ e_ss, const int* __restrict__ e_as_s,
    const int* __restrict__ e_as_d, const int* __restrict__ e_us,
    unsigned* __restrict__ pAS, unsigned* __restrict__ pSS,
    unsigned* __restrict__ pUS, int* __restrict__ gcur){
  __shared__ int cnt[NB];
  __shared__ int seg[NB];
  int bid = blockIdx.x, tid = threadIdx.x;
  int rel, chunk, cap, Erel;
  const int *sp, *dp; unsigned* part;
  if(bid < NCH_AS){ rel=0; chunk=bid; sp=e_as_s; dp=e_as_d; part=pAS; cap=CAP_AS; Erel=EAS; }
  else if(bid < NCH_AS+NCH_SS){ rel=1; chunk=bid-NCH_AS; sp=e_ss; dp=e_ss+ESS; part=pSS; cap=CAP_SS; Erel=ESS; }
  else { rel=2; chunk=bid-NCH_AS-NCH_SS; sp=e_us; dp=e_us+EUS; part=pUS; cap=CAP_US; Erel=EUS; }
  int m = Erel - chunk*CHUNK; if(m>CHUNK) m=CHUNK;
  for(int i=tid;i<NB;i+=256) cnt[i]=0;
  __syncthreads();
  unsigned pk[16], meta[16];
  #pragma unroll
  for(int j=0;j<16;j++){
    int idx = j*256+tid;
    meta[j] = 0xFFFFFFFFu;
    if(idx < m){
      long i = (long)chunk*CHUNK + idx;
      int s = sp[i], d = dp[i];
      int b = bucket_of(d);
      int r = atomicAdd(&cnt[b],1);
      pk[j] = ((unsigned)s<<9) | (unsigned)(d - bucket_base(b));
      meta[j] = ((unsigned)b<<16) | (unsigned)r;
    }
  }
  __syncthreads();
  for(int q=tid;q<NB;q+=256){
    int c = cnt[q];
    seg[q] = c ? atomicAdd(&gcur[rel*NB+q], c) : 0;
  }
  __syncthreads();
  #pragma unroll
  for(int j=0;j<16;j++){
    if(meta[j]!=0xFFFFFFFFu){
      int b = meta[j]>>16, r = meta[j]&0xFFFF;
      int pos = seg[b] + r;
      if(pos < cap) part[(long)b*cap + pos] = pk[j];
    }
  }
}

// Exclusive scan of clamped bucket sizes -> per-bucket col base offsets.
__global__ void kbscan(const int* __restrict__ gcur, int* __restrict__ boff){
  __shared__ int s1[256];
  int t = threadIdx.x;
  for(int rel=0; rel<3; rel++){
    int cap = (rel==0)?CAP_AS:((rel==1)?CAP_SS:CAP_US);
    int g0 = gcur[rel*NB + 2*t], g1 = gcur[rel*NB + 2*t+1];
    int a0 = g0<cap?g0:cap, a1 = g1<cap?g1:cap;
    s1[t] = a0+a1;
    __syncthreads();
    for(int off=1; off<256; off<<=1){
      int x = s1[t];
      int y = (t>=off)?s1[t-off]:0;
      __syncthreads();
      s1[t] = x+y;
      __syncthreads();
    }
    int e2 = s1[t]-(a0+a1);
    boff[rel*NB + 2*t]   = e2;
    boff[rel*NB + 2*t+1] = e2+a0;
    __syncthreads();
  }
}

// Per-bucket counting sort -> CSR (rp, deg, col). Bucket edges <= 34KB; col
// writes random only within the bucket's contiguous segment (L2-merged).
__global__ __launch_bounds__(256) void ksort(
    const unsigned* __restrict__ pAS, const unsigned* __restrict__ pSS,
    const unsigned* __restrict__ pUS, const int* __restrict__ gcur,
    const int* __restrict__ boff,
    int* __restrict__ colAS, int* __restrict__ colSS, int* __restrict__ colUS,
    int* __restrict__ rpAS, int* __restrict__ rpSS, int* __restrict__ rpUS,
    int* __restrict__ degAS, int* __restrict__ degSS, int* __restrict__ degUS){
  __shared__ int degl[512];
  __shared__ int excl[512];
  __shared__ int cur[512];
  __shared__ int s1[256];
  int bid = blockIdx.x;
  int rel = bid >> 9, b = bid & 511;
  const unsigned* part; int cap; int* col; int* rp; int* deg;
  if(rel==0){ part=pAS; cap=CAP_AS; col=colAS; rp=rpAS; deg=degAS; }
  else if(rel==1){ part=pSS; cap=CAP_SS; col=colSS; rp=rpSS; deg=degSS; }
  else { part=pUS; cap=CAP_US; col=colUS; rp=rpUS; deg=degUS; }
  int tid = threadIdx.x;
  int base_b = bucket_base(b);
  int base_n = (b+1==NB)?NSUB:bucket_base(b+1);
  int width = base_n - base_b;
  int size = gcur[rel*NB+b]; if(size>cap) size=cap;
  int bo = boff[rel*NB+b];
  const unsigned* pb = part + (long)b*cap;
  degl[tid]=0; degl[256+tid]=0;
  __syncthreads();
  for(int i=tid;i<size;i+=256) atomicAdd(&degl[pb[i]&511u],1);
  __syncthreads();
  int a0=degl[2*tid], a1=degl[2*tid+1];
  s1[tid]=a0+a1;
  __syncthreads();
  for(int off=1; off<256; off<<=1){
    int x=s1[tid];
    int y=(tid>=off)?s1[tid-off]:0;
    __syncthreads();
    s1[tid]=x+y;
    __syncthreads();
  }
  int e2 = s1[tid]-(a0+a1);
  excl[2*tid]=e2;     excl[2*tid+1]=e2+a0;
  cur[2*tid]=e2;      cur[2*tid+1]=e2+a0;
  __syncthreads();
  for(int n=tid;n<width;n+=256){
    rp[base_b+n]  = bo + excl[n];
    deg[base_b+n] = degl[n];
  }
  for(int i=tid;i<size;i+=256){
    unsigned p = pb[i];
    int dl = (int)(p&511u);
    int r = atomicAdd(&cur[dl],1);
    col[bo + r] = (int)(p>>9);
  }
}

__device__ __forceinline__ float gather1(const float* x, size_t idx){ return x[idx]; }
__device__ __forceinline__ float gather1(const u16* x, size_t idx){ return bu2f(x[idx]); }

// Wave-per-dst, register accumulate, no LDS -> full occupancy.
template<typename T, bool MEAN>
__global__ void kaggregate(const T* __restrict__ x, const int* __restrict__ rowptr,
                           const int* __restrict__ deg, const int* __restrict__ col,
                           u16* __restrict__ out, int ndst){
  int gid = blockIdx.x*256 + threadIdx.x;
  int w = gid>>6, lane = gid&63;
  if(w>=ndst) return;
  int s = rowptr[w], d = deg[w];
  float acc = 0.f;
  int i=0;
  for(; i+4<=d; i+=4){
    int s0=col[s+i], s1=col[s+i+1], s2=col[s+i+2], s3=col[s+i+3];
    float a0 = gather1(x, (size_t)s0*HDIM + lane);
    float a1 = gather1(x, (size_t)s1*HDIM + lane);
    float a2 = gather1(x, (size_t)s2*HDIM + lane);
    float a3 = gather1(x, (size_t)s3*HDIM + lane);
    acc += (a0+a1)+(a2+a3);
  }
  for(; i<d; i++){
    int s0=col[s+i];
    acc += gather1(x, (size_t)s0*HDIM + lane);
  }
  float sc = 1.f;
  if(MEAN) sc = 1.f/(float)(d>1?d:1);
  out[(size_t)w*HDIM + lane] = f2bu(acc*sc);
}

// MFMA GEMM (unchanged, verified in R3).
__global__ __launch_bounds__(256) void kgemmM(
    const u16* __restrict__ aggSS, const u16* __restrict__ aggAS,
    const u16* __restrict__ aggUS, const u16* __restrict__ subIn,
    const u16* __restrict__ Wg, const float* __restrict__ bsum,
    u16* __restrict__ subOut){
  __shared__ u16 ldsW[64*264];
  __shared__ float ldsB[64];
  int tid = threadIdx.x;
  const unsigned* wg32 = (const unsigned*)Wg;
  for(int i=tid; i<8192; i+=256){
    int o = i>>7, k2 = i&127;
    ((unsigned*)ldsW)[o*132 + k2] = wg32[i];
  }
  if(tid<64) ldsB[tid] = bsum[tid];
  __syncthreads();
  int lane = tid&63, wid = tid>>6;
  long row0 = (long)blockIdx.x*64 + wid*16;
  const u16* arrs[4] = {aggSS, aggAS, aggUS, subIn};
  v4f acc[4] = {};
  long rowl = row0 + (lane&15);
  int kq = (lane>>4)*8;
  #pragma unroll
  for(int s=0;s<8;s++){
    const u16* ap = arrs[s>>1] + rowl*64 + (s&1)*32 + kq;
    v8s a = *(const v8s*)ap;
    #pragma unroll
    for(int t=0;t<4;t++){
      v8s bf = *(const v8s*)&ldsW[(t*16+(lane&15))*264 + s*32 + kq];
      acc[t] = __builtin_amdgcn_mfma_f32_16x16x32_bf16(a, bf, acc[t], 0,0,0);
    }
  }
  int m0 = (lane>>4)*4;
  #pragma unroll
  for(int t=0;t<4;t++){
    int o = t*16 + (lane&15);
    float bb = ldsB[o];
    #pragma unroll
    for(int r=0;r<4;r++){
      float h = acc[t][r] + bb;
      h = fmaxf(h, 0.f);
      subOut[(row0 + m0 + r)*64 + o] = f2bu(h);
    }
  }
}

// head: softmax(sub @ Wf^T + bf) -> FLOAT32 out
__global__ void khead(const u16* __restrict__ sub, const float* __restrict__ Wf,
                      const float* __restrict__ bfv, float* __restrict__ out, int n){
  __shared__ float w[6*64];
  __shared__ float b[6];
  for(int j=threadIdx.x; j<384; j+=256) w[j]=Wf[j];
  if(threadIdx.x<6) b[threadIdx.x]=bfv[threadIdx.x];
  __syncthreads();
  int i = blockIdx.x*256 + threadIdx.x;
  if(i>=n) return;
  const unsigned int* row = (const unsigned int*)(sub + (size_t)i*HDIM);
  float d0=b[0],d1=b[1],d2=b[2],d3=b[3],d4=b[4],d5=b[5];
  #pragma unroll 8
  for(int k2=0;k2<32;k2++){
    unsigned int v = row[k2];
    float lo = bu2f((u16)(v&0xffffu));
    float hi = bu2f((u16)(v>>16));
    int k = 2*k2;
    d0 += lo*w[0*64+k] + hi*w[0*64+k+1];
    d1 += lo*w[1*64+k] + hi*w[1*64+k+1];
    d2 += lo*w[2*64+k] + hi*w[2*64+k+1];
    d3 += lo*w[3*64+k] + hi*w[3*64+k+1];
    d4 += lo*w[4*64+k] + hi*w[4*64+k+1];
    d5 += lo*w[5*64+k] + hi*w[5*64+k+1];
  }
  float m = fmaxf(fmaxf(fmaxf(d0,d1),fmaxf(d2,d3)),fmaxf(d4,d5));
  float e0=expf(d0-m), e1=expf(d1-m), e2=expf(d2-m);
  float e3=expf(d3-m), e4=expf(d4-m), e5=expf(d5-m);
  float inv = 1.0f/(e0+e1+e2+e3+e4+e5);
  float2* op = (float2*)(out + (size_t)i*6);
  float2 r0; r0.x=e0*inv; r0.y=e1*inv;
  float2 r1; r1.x=e2*inv; r1.y=e3*inv;
  float2 r2; r2.x=e4*inv; r2.y=e5*inv;
  op[0]=r0; op[1]=r1; op[2]=r2;
}

extern "C" void kernel_launch(void* const* d_in, const int* in_sizes, int n_in,
                              void* d_out, int out_size, void* d_ws, size_t ws_size,
                              hipStream_t stream) {
  const float* x_sub = (const float*)d_in[0];
  const float* x_agr = (const float*)d_in[1];
  const float* x_urb = (const float*)d_in[2];
  const float* Wl    = (const float*)d_in[3];
  const float* bl    = (const float*)d_in[4];
  const float* Wr    = (const float*)d_in[5];
  const float* Wf    = (const float*)d_in[6];
  const float* bfv   = (const float*)d_in[7];
  const int* e_ss    = (const int*)d_in[8];
  const int* e_as_s  = (const int*)d_in[9];
  const int* e_as_d  = (const int*)d_in[10];
  const int* e_us    = (const int*)d_in[11];
  float* out = (float*)d_out;

  char* ws = (char*)d_ws;
  size_t off = 0;
  auto alloc = [&](size_t bytes)->void*{
    void* p = ws + off; off += (bytes + 255) & ~(size_t)255; return p;
  };
  u16*  subA   = (u16*) alloc((size_t)NSUB*HDIM*2);
  u16*  subB   = (u16*) alloc((size_t)NSUB*HDIM*2);
  u16*  aggSS  = (u16*) alloc((size_t)NSUB*HDIM*2);
  u16*  aggAS  = (u16*) alloc((size_t)NSUB*HDIM*2);
  u16*  aggUS  = (u16*) alloc((size_t)NSUB*HDIM*2);
  unsigned* pAS = (unsigned*)alloc((size_t)NB*CAP_AS*4);
  unsigned* pSS = (unsigned*)alloc((size_t)NB*CAP_SS*4);
  unsigned* pUS = (unsigned*)alloc((size_t)NB*CAP_US*4);
  int*  gcur   = (int*)  alloc((size_t)3*NB*4);
  int*  boff   = (int*)  alloc((size_t)3*NB*4);
  int*  colAS  = (int*)  alloc((size_t)EAS*4);
  int*  colSS  = (int*)  alloc((size_t)ESS*4);
  int*  colUS  = (int*)  alloc((size_t)EUS*4);
  int*  rpAS   = (int*)  alloc((size_t)NSUB*4);
  int*  rpSS   = (int*)  alloc((size_t)NSUB*4);
  int*  rpUS   = (int*)  alloc((size_t)NSUB*4);
  int*  degAS  = (int*)  alloc((size_t)NSUB*4);
  int*  degSS  = (int*)  alloc((size_t)NSUB*4);
  int*  degUS  = (int*)  alloc((size_t)NSUB*4);
  u16*  Wg     = (u16*)  alloc((size_t)3*64*256*2);
  float* bsum  = (float*)alloc((size_t)3*64*4);
  if(off > ws_size){
    fprintf(stderr, "kernel_launch: ws too small: need %zu have %zu\n", off, ws_size);
    return;
  }

  // prep
  kcast<<<CDIV(NSUB*HDIM/4,256),256,0,stream>>>((const float4*)x_sub, (uint2*)subA, NSUB*HDIM/4);
  kprep<<<3,256,0,stream>>>(Wl, Wr, bl, Wg, bsum);
  kzero<<<CDIV(3*NB,256),256,0,stream>>>(gcur, 3*NB);

  // bucket partition -> counting sort -> CSR
  kpart<<<NCH_AS+NCH_SS+NCH_US,256,0,stream>>>(e_ss, e_as_s, e_as_d, e_us,
                                               pAS, pSS, pUS, gcur);
  kbscan<<<1,256,0,stream>>>(gcur, boff);
  ksort<<<3*NB,256,0,stream>>>(pAS, pSS, pUS, gcur, boff,
                               colAS, colSS, colUS,
                               rpAS, rpSS, rpUS,
                               degAS, degSS, degUS);

  // one-time agr/urb aggregations
  const int aggBlocks = CDIV(NSUB*64,256);
  kaggregate<float,false><<<aggBlocks,256,0,stream>>>(x_agr, rpAS, degAS, colAS, aggAS, NSUB);
  kaggregate<float,false><<<aggBlocks,256,0,stream>>>(x_urb, rpUS, degUS, colUS, aggUS, NSUB);

  const int gemmBlocks = NSUB/64;
  // layer 0 (ss aggr = sum)
  kaggregate<u16,false><<<aggBlocks,256,0,stream>>>(subA, rpSS, degSS, colSS, aggSS, NSUB);
  kgemmM<<<gemmBlocks,256,0,stream>>>(aggSS, aggAS, aggUS, subA, Wg + 0*16384, bsum + 0*64, subB);
  // layer 1 (ss aggr = mean)
  kaggregate<u16,true><<<aggBlocks,256,0,stream>>>(subB, rpSS, degSS, colSS, aggSS, NSUB);
  kgemmM<<<gemmBlocks,256,0,stream>>>(aggSS, aggAS, aggUS, subB, Wg + 1*16384, bsum + 1*64, subA);
  // layer 2 (ss aggr = mean)
  kaggregate<u16,true><<<aggBlocks,256,0,stream>>>(subA, rpSS, degSS, colSS, aggSS, NSUB);
  kgemmM<<<gemmBlocks,256,0,stream>>>(aggSS, aggAS, aggUS, subA, Wg + 2*16384, bsum + 2*64, subB);

  // head
  khead<<<CDIV(NSUB,256),256,0,stream>>>(subB, Wf, bfv, out, NSUB);
}

// Round 5
// 915.867 us; speedup vs baseline: 5.4548x; 1.1270x over previous
//
#include <hip/hip_runtime.h>
#include <cstdio>
#include <cstdint>

// HeteroGraph 3-layer SAGE on MI355X — R5.
// R4 post-mortem: as-gather reads f32 rows (256B/edge, 1GB logical); L3 only
// absorbs half (FETCH 498MB), 179us. R5: gather from bf16 copies of
// x_agr/x_urb (tables alias the dead partition buffers; f32 fallback if ws
// too small), unroll-8 gather with readfirstlane'd row bounds, fewer launches
// (fused as+us agg, casts fused, gcur zeroing folded into kprep).

#define NSUB 200000
#define NAGR 400000
#define NURB 200000
#define HDIM 64
#define ESS 2000000
#define EAS 4000000
#define EUS 2000000
#define NB 512
#define CAP_AS 8608
#define CAP_SS 4320
#define CAP_US 4320
#define CHUNK 4096
#define NCH_AS 977
#define NCH_SS 489
#define NCH_US 489
#define CDIV(a,b) (((a)+(b)-1)/(b))

using u16 = unsigned short;
typedef __attribute__((ext_vector_type(8))) short v8s;
typedef __attribute__((ext_vector_type(4))) float v4f;

__device__ __forceinline__ float bu2f(u16 u){
  union { unsigned int i; float f; } c; c.i = ((unsigned int)u) << 16; return c.f;
}
__device__ __forceinline__ u16 f2bu(float x){
  union { float f; unsigned int i; } c; c.f = x;
  unsigned int r = c.i + 0x7fffu + ((c.i >> 16) & 1u);
  return (u16)(r >> 16);
}
__device__ __forceinline__ int bucket_of(int d){
  return (int)(((unsigned long long)(unsigned)d * NB) / NSUB);
}
__device__ __forceinline__ int bucket_base(int b){
  return (int)(((unsigned long long)b * NSUB + NB - 1) / NB);
}

__global__ void kcast(const float4* __restrict__ in, uint2* __restrict__ outp, int n4){
  int i = blockIdx.x*256 + threadIdx.x;
  if(i<n4){
    float4 v = in[i];
    uint2 o;
    o.x = (unsigned int)f2bu(v.x) | ((unsigned int)f2bu(v.y)<<16);
    o.y = (unsigned int)f2bu(v.z) | ((unsigned int)f2bu(v.w)<<16);
    outp[i]=o;
  }
}

// fused cast of x_agr and x_urb -> bf16 (runs AFTER ksort; dst aliases pXX)
__global__ void kcast2(const float4* __restrict__ a, uint2* __restrict__ oa, int n4a,
                       const float4* __restrict__ u, uint2* __restrict__ ou, int n4u){
  int i = blockIdx.x*256 + threadIdx.x;
  const float4* src; uint2* dst; int idx;
  if(i < n4a){ src=a; dst=oa; idx=i; }
  else { idx = i - n4a; if(idx >= n4u) return; src=u; dst=ou; }
  float4 v = src[idx];
  uint2 o;
  o.x = (unsigned int)f2bu(v.x) | ((unsigned int)f2bu(v.y)<<16);
  o.y = (unsigned int)f2bu(v.z) | ((unsigned int)f2bu(v.w)<<16);
  dst[idx]=o;
}

// Per-layer weights -> bf16 transposed [o][k=256] (+bias sum); also zeros gcur.
__global__ void kprep(const float* __restrict__ Wl, const float* __restrict__ Wr,
                      const float* __restrict__ bl, u16* __restrict__ Wg,
                      float* __restrict__ bsum, int* __restrict__ gcur){
  int l = blockIdx.x, tid = threadIdx.x;
  for(int i=tid; i<16384; i+=256){
    int o = i>>8, k = i&255, a = k>>6, kk = k&63;
    float v;
    if(a<3) v = Wl[(((size_t)l*3+a)*64+o)*64+kk];
    else    v = Wr[(((size_t)l*3+0)*64+o)*64+kk]
              + Wr[(((size_t)l*3+1)*64+o)*64+kk]
              + Wr[(((size_t)l*3+2)*64+o)*64+kk];
    Wg[((size_t)l*64+o)*256 + k] = f2bu(v);
  }
  if(tid<64) bsum[l*64+tid] = bl[(l*3+0)*64+tid] + bl[(l*3+1)*64+tid] + bl[(l*3+2)*64+tid];
  for(int i=tid;i<NB;i+=256) gcur[l*NB+i]=0;
}

// Fused 3-relation bucket partition (validated R3/R4).
__global__ __launch_bounds__(256) void kpart(
    const int* __restrict__ e_ss, const int* __restrict__ e_as_s,
    const int* __restrict__ e_as_d, const int* __restrict__ e_us,
    unsigned* __restrict__ pAS, unsigned* __restrict__ pSS,
    unsigned* __restrict__ pUS, int* __restrict__ gcur){
  __shared__ int cnt[NB];
  __shared__ int seg[NB];
  int bid = blockIdx.x, tid = threadIdx.x;
  int rel, chunk, cap, Erel;
  const int *sp, *dp; unsigned* part;
  if(bid < NCH_AS){ rel=0; chunk=bid; sp=e_as_s; dp=e_as_d; part=pAS; cap=CAP_AS; Erel=EAS; }
  else if(bid < NCH_AS+NCH_SS){ rel=1; chunk=bid-NCH_AS; sp=e_ss; dp=e_ss+ESS; part=pSS; cap=CAP_SS; Erel=ESS; }
  else { rel=2; chunk=bid-NCH_AS-NCH_SS; sp=e_us; dp=e_us+EUS; part=pUS; cap=CAP_US; Erel=EUS; }
  int m = Erel - chunk*CHUNK; if(m>CHUNK) m=CHUNK;
  for(int i=tid;i<NB;i+=256) cnt[i]=0;
  __syncthreads();
  unsigned pk[16], meta[16];
  #pragma unroll
  for(int j=0;j<16;j++){
    int idx = j*256+tid;
    meta[j] = 0xFFFFFFFFu;
    if(idx < m){
      long i = (long)chunk*CHUNK + idx;
      int s = sp[i], d = dp[i];
      int b = bucket_of(d);
      int r = atomicAdd(&cnt[b],1);
      pk[j] = ((unsigned)s<<9) | (unsigned)(d - bucket_base(b));
      meta[j] = ((unsigned)b<<16) | (unsigned)r;
    }
  }
  __syncthreads();
  for(int q=tid;q<NB;q+=256){
    int c = cnt[q];
    seg[q] = c ? atomicAdd(&gcur[rel*NB+q], c) : 0;
  }
  __syncthreads();
  #pragma unroll
  for(int j=0;j<16;j++){
    if(meta[j]!=0xFFFFFFFFu){
      int b = meta[j]>>16, r = meta[j]&0xFFFF;
      int pos = seg[b] + r;
      if(pos < cap) part[(long)b*cap + pos] = pk[j];
    }
  }
}

// Exclusive scan of clamped bucket sizes -> per-bucket col base offsets.
__global__ void kbscan(const int* __restrict__ gcur, int* __restrict__ boff){
  __shared__ int s1[256];
  int t = threadIdx.x;
  for(int rel=0; rel<3; rel++){
    int cap = (rel==0)?CAP_AS:((rel==1)?CAP_SS:CAP_US);
    int g0 = gcur[rel*NB + 2*t], g1 = gcur[rel*NB + 2*t+1];
    int a0 = g0<cap?g0:cap, a1 = g1<cap?g1:cap;
    s1[t] = a0+a1;
    __syncthreads();
    for(int off=1; off<256; off<<=1){
      int x = s1[t];
      int y = (t>=off)?s1[t-off]:0;
      __syncthreads();
      s1[t] = x+y;
      __syncthreads();
    }
    int e2 = s1[t]-(a0+a1);
    boff[rel*NB + 2*t]   = e2;
    boff[rel*NB + 2*t+1] = e2+a0;
    __syncthreads();
  }
}

// Per-bucket counting sort -> CSR (validated R4).
__global__ __launch_bounds__(256) void ksort(
    const unsigned* __restrict__ pAS, const unsigned* __restrict__ pSS,
    const unsigned* __restrict__ pUS, const int* __restrict__ gcur,
    const int* __restrict__ boff,
    int* __restrict__ colAS, int* __restrict__ colSS, int* __restrict__ colUS,
    int* __restrict__ rpAS, int* __restrict__ rpSS, int* __restrict__ rpUS,
    int* __restrict__ degAS, int* __restrict__ degSS, int* __restrict__ degUS){
  __shared__ int degl[512];
  __shared__ int excl[512];
  __shared__ int cur[512];
  __shared__ int s1[256];
  int bid = blockIdx.x;
  int rel = bid >> 9, b = bid & 511;
  const unsigned* part; int cap; int* col; int* rp; int* deg;
  if(rel==0){ part=pAS; cap=CAP_AS; col=colAS; rp=rpAS; deg=degAS; }
  else if(rel==1){ part=pSS; cap=CAP_SS; col=colSS; rp=rpSS; deg=degSS; }
  else { part=pUS; cap=CAP_US; col=colUS; rp=rpUS; deg=degUS; }
  int tid = threadIdx.x;
  int base_b = bucket_base(b);
  int base_n = (b+1==NB)?NSUB:bucket_base(b+1);
  int width = base_n - base_b;
  int size = gcur[rel*NB+b]; if(size>cap) size=cap;
  int bo = boff[rel*NB+b];
  const unsigned* pb = part + (long)b*cap;
  degl[tid]=0; degl[256+tid]=0;
  __syncthreads();
  for(int i=tid;i<size;i+=256) atomicAdd(&degl[pb[i]&511u],1);
  __syncthreads();
  int a0=degl[2*tid], a1=degl[2*tid+1];
  s1[tid]=a0+a1;
  __syncthreads();
  for(int off=1; off<256; off<<=1){
    int x=s1[tid];
    int y=(tid>=off)?s1[tid-off]:0;
    __syncthreads();
    s1[tid]=x+y;
    __syncthreads();
  }
  int e2 = s1[tid]-(a0+a1);
  excl[2*tid]=e2;     excl[2*tid+1]=e2+a0;
  cur[2*tid]=e2;      cur[2*tid+1]=e2+a0;
  __syncthreads();
  for(int n=tid;n<width;n+=256){
    rp[base_b+n]  = bo + excl[n];
    deg[base_b+n] = degl[n];
  }
  for(int i=tid;i<size;i+=256){
    unsigned p = pb[i];
    int dl = (int)(p&511u);
    int r = atomicAdd(&cur[dl],1);
    col[bo + r] = (int)(p>>9);
  }
}

__device__ __forceinline__ float gather1(const float* x, size_t idx){ return x[idx]; }
__device__ __forceinline__ float gather1(const u16* x, size_t idx){ return bu2f(x[idx]); }

// Wave-per-dst register-accumulate gather; unroll-8, scalar row bounds.
template<typename T, bool MEAN>
__device__ __forceinline__ void agg_one(const T* __restrict__ x,
    const int* __restrict__ rowptr, const int* __restrict__ deg,
    const int* __restrict__ col, u16* __restrict__ out, int w, int lane){
  int s = __builtin_amdgcn_readfirstlane(rowptr[w]);
  int d = __builtin_amdgcn_readfirstlane(deg[w]);
  float acc = 0.f;
  int i=0;
  for(; i+8<=d; i+=8){
    int sj[8];
    #pragma unroll
    for(int j=0;j<8;j++) sj[j]=col[s+i+j];
    float a[8];
    #pragma unroll
    for(int j=0;j<8;j++) a[j]=gather1(x,(size_t)sj[j]*HDIM+lane);
    acc += ((a[0]+a[1])+(a[2]+a[3])) + ((a[4]+a[5])+(a[6]+a[7]));
  }
  for(; i<d; i++) acc += gather1(x,(size_t)col[s+i]*HDIM+lane);
  float sc = 1.f;
  if(MEAN) sc = 1.f/(float)(d>1?d:1);
  out[(size_t)w*HDIM + lane] = f2bu(acc*sc);
}

template<typename T, bool MEAN>
__global__ void kaggregate(const T* __restrict__ x, const int* __restrict__ rowptr,
                           const int* __restrict__ deg, const int* __restrict__ col,
                           u16* __restrict__ out, int ndst){
  int gid = blockIdx.x*256 + threadIdx.x;
  int w = gid>>6, lane = gid&63;
  if(w>=ndst) return;
  agg_one<T,MEAN>(x, rowptr, deg, col, out, w, lane);
}

// fused as+us aggregation (independent; one launch)
template<typename T>
__global__ void kaggAU(const T* __restrict__ xa, const int* __restrict__ rpA,
                       const int* __restrict__ degA, const int* __restrict__ colA,
                       u16* __restrict__ outA,
                       const T* __restrict__ xu, const int* __restrict__ rpU,
                       const int* __restrict__ degU, const int* __restrict__ colU,
                       u16* __restrict__ outU){
  int gid = blockIdx.x*256 + threadIdx.x;
  int w = gid>>6, lane = gid&63;
  if(w < NSUB)        agg_one<T,false>(xa, rpA, degA, colA, outA, w, lane);
  else if(w < 2*NSUB) agg_one<T,false>(xu, rpU, degU, colU, outU, w-NSUB, lane);
}

// MFMA GEMM (verified R3/R4).
__global__ __launch_bounds__(256) void kgemmM(
    const u16* __restrict__ aggSS, const u16* __restrict__ aggAS,
    const u16* __restrict__ aggUS, const u16* __restrict__ subIn,
    const u16* __restrict__ Wg, const float* __restrict__ bsum,
    u16* __restrict__ subOut){
  __shared__ u16 ldsW[64*264];
  __shared__ float ldsB[64];
  int tid = threadIdx.x;
  const unsigned* wg32 = (const unsigned*)Wg;
  for(int i=tid; i<8192; i+=256){
    int o = i>>7, k2 = i&127;
    ((unsigned*)ldsW)[o*132 + k2] = wg32[i];
  }
  if(tid<64) ldsB[tid] = bsum[tid];
  __syncthreads();
  int lane = tid&63, wid = tid>>6;
  long row0 = (long)blockIdx.x*64 + wid*16;
  const u16* arrs[4] = {aggSS, aggAS, aggUS, subIn};
  v4f acc[4] = {};
  long rowl = row0 + (lane&15);
  int kq = (lane>>4)*8;
  #pragma unroll
  for(int s=0;s<8;s++){
    const u16* ap = arrs[s>>1] + rowl*64 + (s&1)*32 + kq;
    v8s a = *(const v8s*)ap;
    #pragma unroll
    for(int t=0;t<4;t++){
      v8s bf = *(const v8s*)&ldsW[(t*16+(lane&15))*264 + s*32 + kq];
      acc[t] = __builtin_amdgcn_mfma_f32_16x16x32_bf16(a, bf, acc[t], 0,0,0);
    }
  }
  int m0 = (lane>>4)*4;
  #pragma unroll
  for(int t=0;t<4;t++){
    int o = t*16 + (lane&15);
    float bb = ldsB[o];
    #pragma unroll
    for(int r=0;r<4;r++){
      float h = acc[t][r] + bb;
      h = fmaxf(h, 0.f);
      subOut[(row0 + m0 + r)*64 + o] = f2bu(h);
    }
  }
}

// head: softmax(sub @ Wf^T + bf) -> FLOAT32 out
__global__ void khead(const u16* __restrict__ sub, const float* __restrict__ Wf,
                      const float* __restrict__ bfv, float* __restrict__ out, int n){
  __shared__ float w[6*64];
  __shared__ float b[6];
  for(int j=threadIdx.x; j<384; j+=256) w[j]=Wf[j];
  if(threadIdx.x<6) b[threadIdx.x]=bfv[threadIdx.x];
  __syncthreads();
  int i = blockIdx.x*256 + threadIdx.x;
  if(i>=n) return;
  const unsigned int* row = (const unsigned int*)(sub + (size_t)i*HDIM);
  float d0=b[0],d1=b[1],d2=b[2],d3=b[3],d4=b[4],d5=b[5];
  #pragma unroll 8
  for(int k2=0;k2<32;k2++){
    unsigned int v = row[k2];
    float lo = bu2f((u16)(v&0xffffu));
    float hi = bu2f((u16)(v>>16));
    int k = 2*k2;
    d0 += lo*w[0*64+k] + hi*w[0*64+k+1];
    d1 += lo*w[1*64+k] + hi*w[1*64+k+1];
    d2 += lo*w[2*64+k] + hi*w[2*64+k+1];
    d3 += lo*w[3*64+k] + hi*w[3*64+k+1];
    d4 += lo*w[4*64+k] + hi*w[4*64+k+1];
    d5 += lo*w[5*64+k] + hi*w[5*64+k+1];
  }
  float m = fmaxf(fmaxf(fmaxf(d0,d1),fmaxf(d2,d3)),fmaxf(d4,d5));
  float e0=expf(d0-m), e1=expf(d1-m), e2=expf(d2-m);
  float e3=expf(d3-m), e4=expf(d4-m), e5=expf(d5-m);
  float inv = 1.0f/(e0+e1+e2+e3+e4+e5);
  float2* op = (float2*)(out + (size_t)i*6);
  float2 r0; r0.x=e0*inv; r0.y=e1*inv;
  float2 r1; r1.x=e2*inv; r1.y=e3*inv;
  float2 r2; r2.x=e4*inv; r2.y=e5*inv;
  op[0]=r0; op[1]=r1; op[2]=r2;
}

extern "C" void kernel_launch(void* const* d_in, const int* in_sizes, int n_in,
                              void* d_out, int out_size, void* d_ws, size_t ws_size,
                              hipStream_t stream) {
  const float* x_sub = (const float*)d_in[0];
  const float* x_agr = (const float*)d_in[1];
  const float* x_urb = (const float*)d_in[2];
  const float* Wl    = (const float*)d_in[3];
  const float* bl    = (const float*)d_in[4];
  const float* Wr    = (const float*)d_in[5];
  const float* Wf    = (const float*)d_in[6];
  const float* bfv   = (const float*)d_in[7];
  const int* e_ss    = (const int*)d_in[8];
  const int* e_as_s  = (const int*)d_in[9];
  const int* e_as_d  = (const int*)d_in[10];
  const int* e_us    = (const int*)d_in[11];
  float* out = (float*)d_out;

  char* ws = (char*)d_ws;
  size_t off = 0;
  auto alloc = [&](size_t bytes)->void*{
    void* p = ws + off; off += (bytes + 255) & ~(size_t)255; return p;
  };
  u16*  subA   = (u16*) alloc((size_t)NSUB*HDIM*2);
  u16*  subB   = (u16*) alloc((size_t)NSUB*HDIM*2);
  u16*  aggSS  = (u16*) alloc((size_t)NSUB*HDIM*2);
  u16*  aggAS  = (u16*) alloc((size_t)NSUB*HDIM*2);
  u16*  aggUS  = (u16*) alloc((size_t)NSUB*HDIM*2);
  int*  colAS  = (int*)  alloc((size_t)EAS*4);
  int*  colSS  = (int*)  alloc((size_t)ESS*4);
  int*  colUS  = (int*)  alloc((size_t)EUS*4);
  int*  rpAS   = (int*)  alloc((size_t)NSUB*4);
  int*  rpSS   = (int*)  alloc((size_t)NSUB*4);
  int*  rpUS   = (int*)  alloc((size_t)NSUB*4);
  int*  degAS  = (int*)  alloc((size_t)NSUB*4);
  int*  degSS  = (int*)  alloc((size_t)NSUB*4);
  int*  degUS  = (int*)  alloc((size_t)NSUB*4);
  int*  gcur   = (int*)  alloc((size_t)3*NB*4);
  int*  boff   = (int*)  alloc((size_t)3*NB*4);
  u16*  Wg     = (u16*)  alloc((size_t)3*64*256*2);
  float* bsum  = (float*)alloc((size_t)3*64*4);
  size_t off0 = off;
  // partition buffers (dead after ksort) — bf16 agr/urb tables alias them
  unsigned* pAS = (unsigned*)alloc((size_t)NB*CAP_AS*4);
  unsigned* pSS = (unsigned*)alloc((size_t)NB*CAP_SS*4);
  unsigned* pUS = (unsigned*)alloc((size_t)NB*CAP_US*4);
  size_t end_part = off;
  u16* agr16 = (u16*)(ws + off0);
  u16* urb16 = agr16 + (size_t)NAGR*HDIM;
  size_t end_cast = off0 + ((size_t)NAGR+NURB)*HDIM*2;
  size_t need_full = end_part > end_cast ? end_part : end_cast;
  bool bf16_gather = (ws_size >= need_full);
  if(ws_size < end_part){
    fprintf(stderr, "kernel_launch: ws too small: need %zu have %zu\n", end_part, ws_size);
    return;
  }

  // prep
  kcast<<<CDIV(NSUB*HDIM/4,256),256,0,stream>>>((const float4*)x_sub, (uint2*)subA, NSUB*HDIM/4);
  kprep<<<3,256,0,stream>>>(Wl, Wr, bl, Wg, bsum, gcur);

  // bucket partition -> counting sort -> CSR
  kpart<<<NCH_AS+NCH_SS+NCH_US,256,0,stream>>>(e_ss, e_as_s, e_as_d, e_us,
                                               pAS, pSS, pUS, gcur);
  kbscan<<<1,256,0,stream>>>(gcur, boff);
  ksort<<<3*NB,256,0,stream>>>(pAS, pSS, pUS, gcur, boff,
                               colAS, colSS, colUS,
                               rpAS, rpSS, rpUS,
                               degAS, degSS, degUS);

  // one-time agr/urb aggregations (fused as+us)
  const int auBlocks = CDIV(2*NSUB*64,256);
  if(bf16_gather){
    int n4a = NAGR*HDIM/4, n4u = NURB*HDIM/4;
    kcast2<<<CDIV(n4a+n4u,256),256,0,stream>>>((const float4*)x_agr, (uint2*)agr16, n4a,
                                               (const float4*)x_urb, (uint2*)urb16, n4u);
    kaggAU<u16><<<auBlocks,256,0,stream>>>(agr16, rpAS, degAS, colAS, aggAS,
                                           urb16, rpUS, degUS, colUS, aggUS);
  } else {
    kaggAU<float><<<auBlocks,256,0,stream>>>(x_agr, rpAS, degAS, colAS, aggAS,
                                             x_urb, rpUS, degUS, colUS, aggUS);
  }

  const int aggBlocks = CDIV(NSUB*64,256);
  const int gemmBlocks = NSUB/64;
  // layer 0 (ss aggr = sum)
  kaggregate<u16,false><<<aggBlocks,256,0,stream>>>(subA, rpSS, degSS, colSS, aggSS, NSUB);
  kgemmM<<<gemmBlocks,256,0,stream>>>(aggSS, aggAS, aggUS, subA, Wg + 0*16384, bsum + 0*64, subB);
  // layer 1 (ss aggr = mean)
  kaggregate<u16,true><<<aggBlocks,256,0,stream>>>(subB, rpSS, degSS, colSS, aggSS, NSUB);
  kgemmM<<<gemmBlocks,256,0,stream>>>(aggSS, aggAS, aggUS, subB, Wg + 1*16384, bsum + 1*64, subA);
  // layer 2 (ss aggr = mean)
  kaggregate<u16,true><<<aggBlocks,256,0,stream>>>(subA, rpSS, degSS, colSS, aggSS, NSUB);
  kgemmM<<<gemmBlocks,256,0,stream>>>(aggSS, aggAS, aggUS, subA, Wg + 2*16384, bsum + 2*64, subB);

  // head
  khead<<<CDIV(NSUB,256),256,0,stream>>>(subB, Wf, bfv, out, NSUB);
}